// Round 1
// baseline (1916.047 us; speedup 1.0000x reference)
//
#include <hip/hip_runtime.h>

#define D 128

// ---------------- degree: deg[dst] += 1 per edge (self-loop added as +1 later)
__global__ __launch_bounds__(256) void k_deg(const int* __restrict__ dst,
                                             float* __restrict__ deg, int E) {
  int e = blockIdx.x * 256 + threadIdx.x;
  if (e < E) unsafeAtomicAdd(&deg[dst[e]], 1.0f);
}

// ---------------- dinv = rsqrt(deg + 1)   (self-loop makes deg >= 1)
__global__ __launch_bounds__(256) void k_dinv(const float* __restrict__ deg,
                                              float* __restrict__ dinv, int N) {
  int i = blockIdx.x * 256 + threadIdx.x;
  if (i < N) dinv[i] = rsqrtf(deg[i] + 1.0f);
}

// ---------------- ssum[src] += dinv[dst] per edge (for layer-2 collapse weights)
__global__ __launch_bounds__(256) void k_ssum(const int* __restrict__ src,
                                              const int* __restrict__ dst,
                                              const float* __restrict__ dinv,
                                              float* __restrict__ ssum, int E) {
  int e = blockIdx.x * 256 + threadIdx.x;
  if (e < E) unsafeAtomicAdd(&ssum[src[e]], dinv[dst[e]]);
}

// ---------------- g = (x @ W1) * dinv[row]
// Tile: 64 rows x 64 cols per block (blockIdx.y selects col half).
// LDS: W half 128x64 (32KB) + x tile 64x128 (32KB) = 64KB.
__global__ __launch_bounds__(256) void k_gemm1(const float* __restrict__ x,
                                               const float* __restrict__ W,
                                               const float* __restrict__ dinv,
                                               float* __restrict__ g, int M) {
  __shared__ float Ws[128 * 64];
  __shared__ float xs[64 * 128];
  int t = threadIdx.x;
  int coff = blockIdx.y * 64;
  int row0 = blockIdx.x * 64;

  // stage W[:, coff:coff+64] -> Ws[k][0..63]
  for (int i = t; i < 128 * 64 / 4; i += 256) {
    int k = i >> 4;           // 16 float4 per row of 64
    int c4 = i & 15;
    ((float4*)Ws)[i] = ((const float4*)(W + (size_t)k * D + coff))[c4];
  }
  // stage x rows row0..row0+63 (clamped)
  for (int i = t; i < 64 * 128 / 4; i += 256) {
    int r = row0 + (i >> 5);  // 32 float4 per row of 128
    int rc = r < M ? r : M - 1;
    ((float4*)xs)[i] = ((const float4*)x)[(size_t)rc * (D / 4) + (i & 31)];
  }
  __syncthreads();

  int cg = t & 15;   // 16 col-groups * 4 cols = 64
  int rg = t >> 4;   // 16 row-groups * 4 rows = 64
  float4 acc[4];
  #pragma unroll
  for (int r = 0; r < 4; ++r) acc[r] = make_float4(0.f, 0.f, 0.f, 0.f);

  for (int k0 = 0; k0 < 128; k0 += 4) {
    float4 xr[4];
    #pragma unroll
    for (int r = 0; r < 4; ++r)
      xr[r] = *(const float4*)&xs[(rg * 4 + r) * 128 + k0];
    float4 wv[4];
    #pragma unroll
    for (int j = 0; j < 4; ++j)
      wv[j] = *(const float4*)&Ws[(k0 + j) * 64 + cg * 4];
    #pragma unroll
    for (int j = 0; j < 4; ++j) {
      #pragma unroll
      for (int r = 0; r < 4; ++r) {
        float xv = ((const float*)&xr[r])[j];
        acc[r].x = fmaf(xv, wv[j].x, acc[r].x);
        acc[r].y = fmaf(xv, wv[j].y, acc[r].y);
        acc[r].z = fmaf(xv, wv[j].z, acc[r].z);
        acc[r].w = fmaf(xv, wv[j].w, acc[r].w);
      }
    }
  }

  #pragma unroll
  for (int r = 0; r < 4; ++r) {
    int row = row0 + rg * 4 + r;
    if (row < M) {
      float s = dinv[row];
      float4 a = acc[r];
      a.x *= s; a.y *= s; a.z *= s; a.w *= s;
      *(float4*)&g[(size_t)row * D + coff + cg * 4] = a;
    }
  }
}

// ---------------- scatter: agg[dst] += g[src]  (128 floats per edge)
// One wave per edge; lanes cover 128 cols as float2. Edge indices loaded
// coalesced 64-at-a-time, broadcast via shfl.
__global__ __launch_bounds__(256) void k_scatter(const float* __restrict__ g,
                                                 const int* __restrict__ src,
                                                 const int* __restrict__ dst,
                                                 float* __restrict__ agg, int E) {
  int lane = threadIdx.x & 63;
  int wave = (blockIdx.x * blockDim.x + threadIdx.x) >> 6;
  int nwaves = (gridDim.x * blockDim.x) >> 6;
  for (int base = wave * 64; base < E; base += nwaves * 64) {
    int idx = base + lane;
    int s_l = idx < E ? src[idx] : 0;
    int d_l = idx < E ? dst[idx] : 0;
    int nm = min(64, E - base);
    for (int j = 0; j < nm; ++j) {
      int s = __shfl(s_l, j, 64);
      int d = __shfl(d_l, j, 64);
      float2 v = *(const float2*)(g + (size_t)s * D + lane * 2);
      float* ap = agg + (size_t)d * D + lane * 2;
      unsafeAtomicAdd(ap, v.x);
      unsafeAtomicAdd(ap + 1, v.y);
    }
  }
}

// ---------------- fused epilogue + weighted reduce:
// a1[r][c] = relu(dinv[r]*(agg[r][c] + g[r][c]) + b1[c])
// vpart[blk][c] = sum_r wsum[r]*a1[r][c],  wsum[r] = dinv[r]*(ssum[r]+dinv[r])
__global__ __launch_bounds__(256) void k_reduce(const float* __restrict__ agg,
                                                const float* __restrict__ g,
                                                const float* __restrict__ dinv,
                                                const float* __restrict__ ssum,
                                                const float* __restrict__ b1,
                                                float* __restrict__ vpart, int N) {
  int t = threadIdx.x;
  int c = t & 127;
  int half = t >> 7;
  float bias = b1[c];
  float vloc = 0.f;
  for (int row = blockIdx.x * 2 + half; row < N; row += gridDim.x * 2) {
    float di = dinv[row];
    float w = di * (ssum[row] + di);
    float a = agg[(size_t)row * D + c];
    float gg = g[(size_t)row * D + c];
    float h = fmaf(di, a + gg, bias);
    h = fmaxf(h, 0.f);
    vloc = fmaf(w, h, vloc);
  }
  __shared__ float red[256];
  red[t] = vloc;
  __syncthreads();
  if (t < 128) vpart[(size_t)blockIdx.x * 128 + t] = red[t] + red[t + 128];
}

// ---------------- final: out[c] = (1/N) * sum_k v[k]*W2[k][c] + b2[c]
__global__ __launch_bounds__(128) void k_final(const float* __restrict__ vpart,
                                               int npart,
                                               const float* __restrict__ W2,
                                               const float* __restrict__ b2,
                                               float* __restrict__ out, float invN) {
  __shared__ float vs[128];
  int c = threadIdx.x;
  float s = 0.f;
  for (int b = 0; b < npart; ++b) s += vpart[(size_t)b * 128 + c];
  vs[c] = s;
  __syncthreads();
  float o = 0.f;
  for (int k = 0; k < 128; ++k) o = fmaf(vs[k], W2[k * 128 + c], o);
  out[c] = fmaf(o, invN, b2[c]);
}

extern "C" void kernel_launch(void* const* d_in, const int* in_sizes, int n_in,
                              void* d_out, int out_size, void* d_ws, size_t ws_size,
                              hipStream_t stream) {
  const float* x  = (const float*)d_in[0];
  const int*   ei = (const int*)d_in[1];
  const float* W1 = (const float*)d_in[2];
  const float* b1 = (const float*)d_in[3];
  const float* W2 = (const float*)d_in[4];
  const float* b2 = (const float*)d_in[5];
  float* out = (float*)d_out;

  int N = in_sizes[0] / D;
  int E = in_sizes[1] / 2;
  const int* src = ei;       // edge_index[0]
  const int* dst = ei + E;   // edge_index[1]

  const int K7_BLOCKS = 1024;

  float* ws   = (float*)d_ws;
  float* deg  = ws;                         // N     (zeroed)
  float* ssum = deg + N;                    // N     (zeroed)
  float* aggg = ssum + N;                   // N*D   (zeroed)
  float* dinv = aggg + (size_t)N * D;       // N
  float* g    = dinv + N;                   // N*D
  float* vpart = g + (size_t)N * D;         // K7_BLOCKS*128

  // zero: deg, ssum, aggg (contiguous)
  hipMemsetAsync(d_ws, 0, (size_t)(2 * N + (size_t)N * D) * sizeof(float), stream);

  k_deg<<<(E + 255) / 256, 256, 0, stream>>>(dst, deg, E);
  k_dinv<<<(N + 255) / 256, 256, 0, stream>>>(deg, dinv, N);

  dim3 ggrid((N + 63) / 64, 2);
  k_gemm1<<<ggrid, 256, 0, stream>>>(x, W1, dinv, g, N);

  k_ssum<<<(E + 255) / 256, 256, 0, stream>>>(src, dst, dinv, ssum, E);

  k_scatter<<<2048, 256, 0, stream>>>(g, src, dst, aggg, E);

  k_reduce<<<K7_BLOCKS, 256, 0, stream>>>(aggg, g, dinv, ssum, b1, vpart, N);

  k_final<<<1, 128, 0, stream>>>(vpart, K7_BLOCKS, W2, b2, out, 1.0f / N);
}

// Round 2
// 619.543 us; speedup vs baseline: 3.0927x; 3.0927x over previous
//
#include <hip/hip_runtime.h>

#define D 128

// ---------------- degree histogram: deg[dst]++ per edge
__global__ __launch_bounds__(256) void k_deg(const int* __restrict__ dst,
                                             int* __restrict__ deg, int E) {
  int e = blockIdx.x * 256 + threadIdx.x;
  if (e < E) atomicAdd(&deg[dst[e]], 1);
}

// ---------------- dinv = rsqrt(deg + 1)   (self-loop)
__global__ __launch_bounds__(256) void k_dinv(const int* __restrict__ deg,
                                              float* __restrict__ dinv, int N) {
  int i = blockIdx.x * 256 + threadIdx.x;
  if (i < N) dinv[i] = rsqrtf((float)deg[i] + 1.0f);
}

// ---------------- ssum[src] += dinv[dst] (layer-2 collapse weights)
__global__ __launch_bounds__(256) void k_ssum(const int* __restrict__ src,
                                              const int* __restrict__ dst,
                                              const float* __restrict__ dinv,
                                              float* __restrict__ ssum, int E) {
  int e = blockIdx.x * 256 + threadIdx.x;
  if (e < E) unsafeAtomicAdd(&ssum[src[e]], dinv[dst[e]]);
}

// ---------------- g = (x @ W1) * dinv[row]
__global__ __launch_bounds__(256) void k_gemm1(const float* __restrict__ x,
                                               const float* __restrict__ W,
                                               const float* __restrict__ dinv,
                                               float* __restrict__ g, int M) {
  __shared__ float Ws[128 * 64];
  __shared__ float xs[64 * 128];
  int t = threadIdx.x;
  int coff = blockIdx.y * 64;
  int row0 = blockIdx.x * 64;

  for (int i = t; i < 128 * 64 / 4; i += 256) {
    int k = i >> 4;
    int c4 = i & 15;
    ((float4*)Ws)[i] = ((const float4*)(W + (size_t)k * D + coff))[c4];
  }
  for (int i = t; i < 64 * 128 / 4; i += 256) {
    int r = row0 + (i >> 5);
    int rc = r < M ? r : M - 1;
    ((float4*)xs)[i] = ((const float4*)x)[(size_t)rc * (D / 4) + (i & 31)];
  }
  __syncthreads();

  int cg = t & 15;
  int rg = t >> 4;
  float4 acc[4];
  #pragma unroll
  for (int r = 0; r < 4; ++r) acc[r] = make_float4(0.f, 0.f, 0.f, 0.f);

  for (int k0 = 0; k0 < 128; k0 += 4) {
    float4 xr[4];
    #pragma unroll
    for (int r = 0; r < 4; ++r)
      xr[r] = *(const float4*)&xs[(rg * 4 + r) * 128 + k0];
    float4 wv[4];
    #pragma unroll
    for (int j = 0; j < 4; ++j)
      wv[j] = *(const float4*)&Ws[(k0 + j) * 64 + cg * 4];
    #pragma unroll
    for (int j = 0; j < 4; ++j) {
      #pragma unroll
      for (int r = 0; r < 4; ++r) {
        float xv = ((const float*)&xr[r])[j];
        acc[r].x = fmaf(xv, wv[j].x, acc[r].x);
        acc[r].y = fmaf(xv, wv[j].y, acc[r].y);
        acc[r].z = fmaf(xv, wv[j].z, acc[r].z);
        acc[r].w = fmaf(xv, wv[j].w, acc[r].w);
      }
    }
  }

  #pragma unroll
  for (int r = 0; r < 4; ++r) {
    int row = row0 + rg * 4 + r;
    if (row < M) {
      float s = dinv[row];
      float4 a = acc[r];
      a.x *= s; a.y *= s; a.z *= s; a.w *= s;
      *(float4*)&g[(size_t)row * D + coff + cg * 4] = a;
    }
  }
}

// ---------------- scan stage 1: per-block (1024 elems) sums
__global__ __launch_bounds__(256) void k_scan1(const int* __restrict__ deg,
                                               int* __restrict__ bsum, int N) {
  int t = threadIdx.x;
  int base = blockIdx.x * 1024;
  int s = 0;
  for (int i = t; i < 1024; i += 256) {
    int idx = base + i;
    if (idx < N) s += deg[idx];
  }
  __shared__ int red[256];
  red[t] = s;
  __syncthreads();
  for (int off = 128; off > 0; off >>= 1) {
    if (t < off) red[t] += red[t + off];
    __syncthreads();
  }
  if (t == 0) bsum[blockIdx.x] = red[0];
}

// ---------------- scan stage 2: serial exclusive scan of block sums (nb ~ 98)
__global__ __launch_bounds__(64) void k_scan2(int* __restrict__ bsum, int nb,
                                              int* __restrict__ offs, int N) {
  if (threadIdx.x == 0) {
    int run = 0;
    for (int b = 0; b < nb; ++b) {
      int v = bsum[b];
      bsum[b] = run;
      run += v;
    }
    offs[N] = run;  // == E
  }
}

// ---------------- scan stage 3: in-block exclusive scan + write offs/cursor
__global__ __launch_bounds__(256) void k_scan3(const int* __restrict__ deg,
                                               const int* __restrict__ bsum,
                                               int* __restrict__ offs,
                                               int* __restrict__ cursor, int N) {
  int t = threadIdx.x;
  int base = blockIdx.x * 1024 + t * 4;
  int v[4];
  int s = 0;
  #pragma unroll
  for (int j = 0; j < 4; ++j) {
    int idx = base + j;
    v[j] = (idx < N) ? deg[idx] : 0;
    s += v[j];
  }
  __shared__ int sc[256];
  sc[t] = s;
  __syncthreads();
  for (int off = 1; off < 256; off <<= 1) {
    int x = (t >= off) ? sc[t - off] : 0;
    __syncthreads();
    sc[t] += x;
    __syncthreads();
  }
  int p = bsum[blockIdx.x] + sc[t] - s;  // exclusive prefix for this thread
  #pragma unroll
  for (int j = 0; j < 4; ++j) {
    int idx = base + j;
    if (idx < N) {
      offs[idx] = p;
      cursor[idx] = p;
      p += v[j];
    }
  }
}

// ---------------- bucket fill: CSR edge list sorted by dst
__global__ __launch_bounds__(256) void k_fill(const int* __restrict__ src,
                                              const int* __restrict__ dst,
                                              int* __restrict__ cursor,
                                              int* __restrict__ bucket, int E) {
  int e = blockIdx.x * 256 + threadIdx.x;
  if (e < E) {
    int pos = atomicAdd(&cursor[dst[e]], 1);
    bucket[pos] = src[e];
  }
}

// ---------------- fused gather-aggregate + epilogue + weighted reduce
// One wave per dst row (grid-stride). acc = sum g[src]; then
// h = relu(dinv[r]*(acc + g[r]) + b1); vloc += dinv[r]*(ssum[r]+dinv[r]) * h.
__global__ __launch_bounds__(256) void k_agg(const float* __restrict__ g,
                                             const int* __restrict__ bucket,
                                             const int* __restrict__ offs,
                                             const float* __restrict__ dinv,
                                             const float* __restrict__ ssum,
                                             const float* __restrict__ b1,
                                             float* __restrict__ vpart, int N) {
  int lane = threadIdx.x & 63;
  int wid = threadIdx.x >> 6;
  int gwave = blockIdx.x * 4 + wid;
  int nwave = gridDim.x * 4;
  int c2 = lane * 2;
  float2 bb = *(const float2*)(b1 + c2);
  float vx = 0.f, vy = 0.f;

  for (int r = gwave; r < N; r += nwave) {
    int beg = offs[r], end = offs[r + 1];
    float ax = 0.f, ay = 0.f;
    int j = beg;
    for (; j + 4 <= end; j += 4) {
      int s0 = bucket[j], s1 = bucket[j + 1], s2 = bucket[j + 2], s3 = bucket[j + 3];
      float2 v0 = *(const float2*)(g + (size_t)s0 * D + c2);
      float2 v1 = *(const float2*)(g + (size_t)s1 * D + c2);
      float2 v2 = *(const float2*)(g + (size_t)s2 * D + c2);
      float2 v3 = *(const float2*)(g + (size_t)s3 * D + c2);
      ax += (v0.x + v1.x) + (v2.x + v3.x);
      ay += (v0.y + v1.y) + (v2.y + v3.y);
    }
    for (; j < end; ++j) {
      int s = bucket[j];
      float2 v = *(const float2*)(g + (size_t)s * D + c2);
      ax += v.x;
      ay += v.y;
    }
    float2 gr = *(const float2*)(g + (size_t)r * D + c2);
    float di = dinv[r];
    float w = di * (ssum[r] + di);
    float hx = fmaxf(fmaf(di, ax + gr.x, bb.x), 0.f);
    float hy = fmaxf(fmaf(di, ay + gr.y, bb.y), 0.f);
    vx = fmaf(w, hx, vx);
    vy = fmaf(w, hy, vy);
  }

  __shared__ float2 red[256];
  red[threadIdx.x] = make_float2(vx, vy);
  __syncthreads();
  if (threadIdx.x < 64) {
    float2 a = red[threadIdx.x], b = red[threadIdx.x + 64];
    float2 c = red[threadIdx.x + 128], d = red[threadIdx.x + 192];
    float2 o = make_float2((a.x + b.x) + (c.x + d.x), (a.y + b.y) + (c.y + d.y));
    *(float2*)(vpart + (size_t)blockIdx.x * D + c2) = o;
  }
}

// ---------------- final: v = sum partials; out = (1/N)*v@W2 + b2
__global__ __launch_bounds__(1024) void k_final(const float* __restrict__ vpart,
                                                int npart,
                                                const float* __restrict__ W2,
                                                const float* __restrict__ b2,
                                                float* __restrict__ out, float invN) {
  __shared__ float seg[8][128];
  __shared__ float vs[128];
  int t = threadIdx.x;
  int c = t & 127, sg = t >> 7;
  float s = 0.f;
  for (int b = sg; b < npart; b += 8) s += vpart[(size_t)b * D + c];
  seg[sg][c] = s;
  __syncthreads();
  if (t < 128) {
    float tot = 0.f;
    #pragma unroll
    for (int k = 0; k < 8; ++k) tot += seg[k][c];
    vs[c] = tot;
  }
  __syncthreads();
  if (t < 128) {
    float o = 0.f;
    for (int k = 0; k < 128; ++k) o = fmaf(vs[k], W2[k * D + c], o);
    out[c] = fmaf(o, invN, b2[c]);
  }
}

extern "C" void kernel_launch(void* const* d_in, const int* in_sizes, int n_in,
                              void* d_out, int out_size, void* d_ws, size_t ws_size,
                              hipStream_t stream) {
  const float* x  = (const float*)d_in[0];
  const int*   ei = (const int*)d_in[1];
  const float* W1 = (const float*)d_in[2];
  const float* b1 = (const float*)d_in[3];
  const float* W2 = (const float*)d_in[4];
  const float* b2 = (const float*)d_in[5];
  float* out = (float*)d_out;

  int N = in_sizes[0] / D;
  int E = in_sizes[1] / 2;
  const int* src = ei;
  const int* dst = ei + E;

  const int NB_SCAN = (N + 1023) / 1024;   // ~98
  const int AGG_BLOCKS = 1024;

  int*   deg    = (int*)d_ws;                    // N (zeroed)
  float* ssum   = (float*)(deg + N);             // N (zeroed)
  float* dinv   = ssum + N;                      // N
  int*   offs   = (int*)(dinv + N);              // N+1
  int*   cursor = offs + N + 1;                  // N
  int*   bsum   = cursor + N;                    // 128
  int*   bucket = bsum + 128;                    // E
  float* g      = (float*)(bucket + E);          // N*D
  float* vpart  = g + (size_t)N * D;             // AGG_BLOCKS*D

  // zero: deg + ssum (contiguous, 800 KB)
  hipMemsetAsync(d_ws, 0, (size_t)(2 * N) * sizeof(float), stream);

  k_deg<<<(E + 255) / 256, 256, 0, stream>>>(dst, deg, E);
  k_dinv<<<(N + 255) / 256, 256, 0, stream>>>(deg, dinv, N);

  dim3 ggrid((N + 63) / 64, 2);
  k_gemm1<<<ggrid, 256, 0, stream>>>(x, W1, dinv, g, N);

  k_ssum<<<(E + 255) / 256, 256, 0, stream>>>(src, dst, dinv, ssum, E);

  k_scan1<<<NB_SCAN, 256, 0, stream>>>(deg, bsum, N);
  k_scan2<<<1, 64, 0, stream>>>(bsum, NB_SCAN, offs, N);
  k_scan3<<<NB_SCAN, 256, 0, stream>>>(deg, bsum, offs, cursor, N);
  k_fill<<<(E + 255) / 256, 256, 0, stream>>>(src, dst, cursor, bucket, E);

  k_agg<<<AGG_BLOCKS, 256, 0, stream>>>(g, bucket, offs, dinv, ssum, b1, vpart, N);

  k_final<<<1, 1024, 0, stream>>>(vpart, AGG_BLOCKS, W2, b2, out, 1.0f / N);
}

// Round 3
// 521.750 us; speedup vs baseline: 3.6723x; 1.1874x over previous
//
#include <hip/hip_runtime.h>

#define D 128

// ---- bf16 pack/unpack helpers (round-to-nearest-even)
__device__ inline unsigned bfr(float f) {
  unsigned u = __float_as_uint(f);
  return (u + 0x7fffu + ((u >> 16) & 1u)) >> 16;
}
__device__ inline unsigned pack2(float lo, float hi) {
  return bfr(lo) | (bfr(hi) << 16);
}

// ---------------- degree histogram: deg[dst]++ per edge
__global__ __launch_bounds__(256) void k_deg(const int* __restrict__ dst,
                                             int* __restrict__ deg, int E) {
  int e = blockIdx.x * 256 + threadIdx.x;
  if (e < E) atomicAdd(&deg[dst[e]], 1);
}

// ---------------- dinv = rsqrt(deg + 1)   (self-loop)
__global__ __launch_bounds__(256) void k_dinv(const int* __restrict__ deg,
                                              float* __restrict__ dinv, int N) {
  int i = blockIdx.x * 256 + threadIdx.x;
  if (i < N) dinv[i] = rsqrtf((float)deg[i] + 1.0f);
}

// ---------------- g = (x @ W1) * dinv[row], stored as packed bf16x2 (64 dwords/row)
__global__ __launch_bounds__(256) void k_gemm1(const float* __restrict__ x,
                                               const float* __restrict__ W,
                                               const float* __restrict__ dinv,
                                               unsigned* __restrict__ gp, int M) {
  __shared__ float Ws[128 * 64];
  __shared__ float xs[64 * 128];
  int t = threadIdx.x;
  int coff = blockIdx.y * 64;
  int row0 = blockIdx.x * 64;

  for (int i = t; i < 128 * 64 / 4; i += 256) {
    int k = i >> 4;
    int c4 = i & 15;
    ((float4*)Ws)[i] = ((const float4*)(W + (size_t)k * D + coff))[c4];
  }
  for (int i = t; i < 64 * 128 / 4; i += 256) {
    int r = row0 + (i >> 5);
    int rc = r < M ? r : M - 1;
    ((float4*)xs)[i] = ((const float4*)x)[(size_t)rc * (D / 4) + (i & 31)];
  }
  __syncthreads();

  int cg = t & 15;
  int rg = t >> 4;
  float4 acc[4];
  #pragma unroll
  for (int r = 0; r < 4; ++r) acc[r] = make_float4(0.f, 0.f, 0.f, 0.f);

  for (int k0 = 0; k0 < 128; k0 += 4) {
    float4 xr[4];
    #pragma unroll
    for (int r = 0; r < 4; ++r)
      xr[r] = *(const float4*)&xs[(rg * 4 + r) * 128 + k0];
    float4 wv[4];
    #pragma unroll
    for (int j = 0; j < 4; ++j)
      wv[j] = *(const float4*)&Ws[(k0 + j) * 64 + cg * 4];
    #pragma unroll
    for (int j = 0; j < 4; ++j) {
      #pragma unroll
      for (int r = 0; r < 4; ++r) {
        float xv = ((const float*)&xr[r])[j];
        acc[r].x = fmaf(xv, wv[j].x, acc[r].x);
        acc[r].y = fmaf(xv, wv[j].y, acc[r].y);
        acc[r].z = fmaf(xv, wv[j].z, acc[r].z);
        acc[r].w = fmaf(xv, wv[j].w, acc[r].w);
      }
    }
  }

  #pragma unroll
  for (int r = 0; r < 4; ++r) {
    int row = row0 + rg * 4 + r;
    if (row < M) {
      float s = dinv[row];
      float4 a = acc[r];
      uint2 p;
      p.x = pack2(a.x * s, a.y * s);
      p.y = pack2(a.z * s, a.w * s);
      *(uint2*)&gp[(size_t)row * 64 + (coff >> 1) + cg * 2] = p;
    }
  }
}

// ---------------- scan stage 1: per-block (1024 elems) sums
__global__ __launch_bounds__(256) void k_scan1(const int* __restrict__ deg,
                                               int* __restrict__ bsum, int N) {
  int t = threadIdx.x;
  int base = blockIdx.x * 1024;
  int s = 0;
  for (int i = t; i < 1024; i += 256) {
    int idx = base + i;
    if (idx < N) s += deg[idx];
  }
  __shared__ int red[256];
  red[t] = s;
  __syncthreads();
  for (int off = 128; off > 0; off >>= 1) {
    if (t < off) red[t] += red[t + off];
    __syncthreads();
  }
  if (t == 0) bsum[blockIdx.x] = red[0];
}

// ---------------- scan stage 2: serial exclusive scan of block sums
__global__ __launch_bounds__(64) void k_scan2(int* __restrict__ bsum, int nb,
                                              int* __restrict__ offs, int N) {
  if (threadIdx.x == 0) {
    int run = 0;
    for (int b = 0; b < nb; ++b) {
      int v = bsum[b];
      bsum[b] = run;
      run += v;
    }
    offs[N] = run;  // == E
  }
}

// ---------------- scan stage 3: in-block exclusive scan + write offs/cursor
__global__ __launch_bounds__(256) void k_scan3(const int* __restrict__ deg,
                                               const int* __restrict__ bsum,
                                               int* __restrict__ offs,
                                               int* __restrict__ cursor, int N) {
  int t = threadIdx.x;
  int base = blockIdx.x * 1024 + t * 4;
  int v[4];
  int s = 0;
  #pragma unroll
  for (int j = 0; j < 4; ++j) {
    int idx = base + j;
    v[j] = (idx < N) ? deg[idx] : 0;
    s += v[j];
  }
  __shared__ int sc[256];
  sc[t] = s;
  __syncthreads();
  for (int off = 1; off < 256; off <<= 1) {
    int x = (t >= off) ? sc[t - off] : 0;
    __syncthreads();
    sc[t] += x;
    __syncthreads();
  }
  int p = bsum[blockIdx.x] + sc[t] - s;
  #pragma unroll
  for (int j = 0; j < 4; ++j) {
    int idx = base + j;
    if (idx < N) {
      offs[idx] = p;
      cursor[idx] = p;
      p += v[j];
    }
  }
}

// ---------------- bucket fill (CSR by dst) + fused ssum[src] += dinv[dst]
__global__ __launch_bounds__(256) void k_fill(const int* __restrict__ src,
                                              const int* __restrict__ dst,
                                              const float* __restrict__ dinv,
                                              int* __restrict__ cursor,
                                              int* __restrict__ bucket,
                                              float* __restrict__ ssum, int E) {
  int e = blockIdx.x * 256 + threadIdx.x;
  if (e < E) {
    int s = src[e], d = dst[e];
    int pos = atomicAdd(&cursor[d], 1);
    bucket[pos] = s;
    unsafeAtomicAdd(&ssum[s], dinv[d]);
  }
}

// ---------------- fused gather-aggregate + epilogue + weighted reduce (bf16 g)
__global__ __launch_bounds__(256) void k_agg(const unsigned* __restrict__ gp,
                                             const int* __restrict__ bucket,
                                             const int* __restrict__ offs,
                                             const float* __restrict__ dinv,
                                             const float* __restrict__ ssum,
                                             const float* __restrict__ b1,
                                             float* __restrict__ vpart, int N) {
  int lane = threadIdx.x & 63;
  int wid = threadIdx.x >> 6;
  int gwave = blockIdx.x * 4 + wid;
  int nwave = gridDim.x * 4;
  float2 bb = *(const float2*)(b1 + lane * 2);
  float vx = 0.f, vy = 0.f;

  for (int r = gwave; r < N; r += nwave) {
    int beg = offs[r], end = offs[r + 1];
    float ax = 0.f, ay = 0.f;
    int j = beg;
    for (; j + 4 <= end; j += 4) {
      int s0 = bucket[j], s1 = bucket[j + 1], s2 = bucket[j + 2], s3 = bucket[j + 3];
      unsigned v0 = gp[(size_t)s0 * 64 + lane];
      unsigned v1 = gp[(size_t)s1 * 64 + lane];
      unsigned v2 = gp[(size_t)s2 * 64 + lane];
      unsigned v3 = gp[(size_t)s3 * 64 + lane];
      ax += (__uint_as_float(v0 << 16) + __uint_as_float(v1 << 16)) +
            (__uint_as_float(v2 << 16) + __uint_as_float(v3 << 16));
      ay += (__uint_as_float(v0 & 0xffff0000u) + __uint_as_float(v1 & 0xffff0000u)) +
            (__uint_as_float(v2 & 0xffff0000u) + __uint_as_float(v3 & 0xffff0000u));
    }
    for (; j < end; ++j) {
      unsigned v = gp[(size_t)bucket[j] * 64 + lane];
      ax += __uint_as_float(v << 16);
      ay += __uint_as_float(v & 0xffff0000u);
    }
    unsigned gr = gp[(size_t)r * 64 + lane];
    float di = dinv[r];
    float w = di * (ssum[r] + di);
    float hx = fmaxf(fmaf(di, ax + __uint_as_float(gr << 16), bb.x), 0.f);
    float hy = fmaxf(fmaf(di, ay + __uint_as_float(gr & 0xffff0000u), bb.y), 0.f);
    vx = fmaf(w, hx, vx);
    vy = fmaf(w, hy, vy);
  }

  __shared__ float2 red[256];
  red[threadIdx.x] = make_float2(vx, vy);
  __syncthreads();
  if (threadIdx.x < 64) {
    float2 a = red[threadIdx.x], b = red[threadIdx.x + 64];
    float2 c = red[threadIdx.x + 128], d = red[threadIdx.x + 192];
    float2 o = make_float2((a.x + b.x) + (c.x + d.x), (a.y + b.y) + (c.y + d.y));
    *(float2*)(vpart + (size_t)blockIdx.x * D + lane * 2) = o;
  }
}

// ---------------- final: v = sum partials; out = (1/N)*v@W2 + b2
__global__ __launch_bounds__(1024) void k_final(const float* __restrict__ vpart,
                                                int npart,
                                                const float* __restrict__ W2,
                                                const float* __restrict__ b2,
                                                float* __restrict__ out, float invN) {
  __shared__ float seg[8][128];
  __shared__ float vs[128];
  int t = threadIdx.x;
  int c = t & 127, sg = t >> 7;
  float s = 0.f;
  for (int b = sg; b < npart; b += 8) s += vpart[(size_t)b * D + c];
  seg[sg][c] = s;
  __syncthreads();
  if (t < 128) {
    float tot = 0.f;
    #pragma unroll
    for (int k = 0; k < 8; ++k) tot += seg[k][c];
    vs[c] = tot;
  }
  __syncthreads();
  if (t < 128) {
    float o = 0.f;
    for (int k = 0; k < 128; ++k) o = fmaf(vs[k], W2[k * D + c], o);
    out[c] = fmaf(o, invN, b2[c]);
  }
}

extern "C" void kernel_launch(void* const* d_in, const int* in_sizes, int n_in,
                              void* d_out, int out_size, void* d_ws, size_t ws_size,
                              hipStream_t stream) {
  const float* x  = (const float*)d_in[0];
  const int*   ei = (const int*)d_in[1];
  const float* W1 = (const float*)d_in[2];
  const float* b1 = (const float*)d_in[3];
  const float* W2 = (const float*)d_in[4];
  const float* b2 = (const float*)d_in[5];
  float* out = (float*)d_out;

  int N = in_sizes[0] / D;
  int E = in_sizes[1] / 2;
  const int* src = ei;
  const int* dst = ei + E;

  const int NB_SCAN = (N + 1023) / 1024;
  const int AGG_BLOCKS = 2048;

  char* p = (char*)d_ws;
  int*   deg    = (int*)p;        p += (size_t)N * 4;
  float* ssum   = (float*)p;      p += (size_t)N * 4;
  float* dinv   = (float*)p;      p += (size_t)N * 4;
  int*   offs   = (int*)p;        p += (size_t)(N + 1) * 4;
  int*   cursor = (int*)p;        p += (size_t)N * 4;
  int*   bsum   = (int*)p;        p += 128 * 4;
  int*   bucket = (int*)p;        p += (size_t)E * 4;
  p = (char*)(((uintptr_t)p + 255) & ~(uintptr_t)255);
  unsigned* gp  = (unsigned*)p;   p += (size_t)N * 64 * 4;
  float* vpart  = (float*)p;

  // zero: deg + ssum (contiguous)
  hipMemsetAsync(d_ws, 0, (size_t)(2 * N) * sizeof(float), stream);

  k_deg<<<(E + 255) / 256, 256, 0, stream>>>(dst, deg, E);
  k_dinv<<<(N + 255) / 256, 256, 0, stream>>>(deg, dinv, N);

  dim3 ggrid((N + 63) / 64, 2);
  k_gemm1<<<ggrid, 256, 0, stream>>>(x, W1, dinv, gp, N);

  k_scan1<<<NB_SCAN, 256, 0, stream>>>(deg, bsum, N);
  k_scan2<<<1, 64, 0, stream>>>(bsum, NB_SCAN, offs, N);
  k_scan3<<<NB_SCAN, 256, 0, stream>>>(deg, bsum, offs, cursor, N);
  k_fill<<<(E + 255) / 256, 256, 0, stream>>>(src, dst, dinv, cursor, bucket, ssum, E);

  k_agg<<<AGG_BLOCKS, 256, 0, stream>>>(gp, bucket, offs, dinv, ssum, b1, vpart, N);

  k_final<<<1, 1024, 0, stream>>>(vpart, AGG_BLOCKS, W2, b2, out, 1.0f / N);
}

// Round 4
// 467.737 us; speedup vs baseline: 4.0964x; 1.1155x over previous
//
#include <hip/hip_runtime.h>

#define D 128

// ---- bf16 pack helpers (round-to-nearest-even)
__device__ inline unsigned bfr(float f) {
  unsigned u = __float_as_uint(f);
  return (u + 0x7fffu + ((u >> 16) & 1u)) >> 16;
}
__device__ inline unsigned pack2(float lo, float hi) {
  return bfr(lo) | (bfr(hi) << 16);
}
__device__ inline float unpk_lo(unsigned v) { return __uint_as_float(v << 16); }
__device__ inline float unpk_hi(unsigned v) { return __uint_as_float(v & 0xffff0000u); }

// ---------------- degree histogram: deg[dst]++ per edge (int4 batched)
__global__ __launch_bounds__(256) void k_deg(const int* __restrict__ dst,
                                             int* __restrict__ deg, int E) {
  int i = (blockIdx.x * 256 + threadIdx.x) * 4;
  if (i + 3 < E) {
    int4 d4 = *(const int4*)(dst + i);
    atomicAdd(&deg[d4.x], 1);
    atomicAdd(&deg[d4.y], 1);
    atomicAdd(&deg[d4.z], 1);
    atomicAdd(&deg[d4.w], 1);
  } else {
    for (int j = i; j < E; ++j) atomicAdd(&deg[dst[j]], 1);
  }
}

// ---------------- dinv = rsqrt(deg + 1)
__global__ __launch_bounds__(256) void k_dinv(const int* __restrict__ deg,
                                              float* __restrict__ dinv, int N) {
  int i = blockIdx.x * 256 + threadIdx.x;
  if (i < N) dinv[i] = rsqrtf((float)deg[i] + 1.0f);
}

// ---------------- scan stage 1: per-block (1024 elems) sums
__global__ __launch_bounds__(256) void k_scan1(const int* __restrict__ deg,
                                               int* __restrict__ bsum, int N) {
  int t = threadIdx.x;
  int base = blockIdx.x * 1024;
  int s = 0;
  for (int i = t; i < 1024; i += 256) {
    int idx = base + i;
    if (idx < N) s += deg[idx];
  }
  __shared__ int red[256];
  red[t] = s;
  __syncthreads();
  for (int off = 128; off > 0; off >>= 1) {
    if (t < off) red[t] += red[t + off];
    __syncthreads();
  }
  if (t == 0) bsum[blockIdx.x] = red[0];
}

// ---------------- scan stage 2: parallel exclusive scan of block sums (nb <= 128)
__global__ __launch_bounds__(128) void k_scan2(int* __restrict__ bsum, int nb,
                                               int* __restrict__ offs, int N) {
  __shared__ int sc[128];
  int t = threadIdx.x;
  int v = (t < nb) ? bsum[t] : 0;
  sc[t] = v;
  __syncthreads();
  #pragma unroll
  for (int off = 1; off < 128; off <<= 1) {
    int x = (t >= off) ? sc[t - off] : 0;
    __syncthreads();
    sc[t] += x;
    __syncthreads();
  }
  if (t < nb) bsum[t] = sc[t] - v;        // exclusive
  if (t == nb - 1) offs[N] = sc[t];       // total == E
}

// ---------------- scan stage 3: in-block exclusive scan + write offs/cursor
__global__ __launch_bounds__(256) void k_scan3(const int* __restrict__ deg,
                                               const int* __restrict__ bsum,
                                               int* __restrict__ offs,
                                               int* __restrict__ cursor, int N) {
  int t = threadIdx.x;
  int base = blockIdx.x * 1024 + t * 4;
  int v[4];
  int s = 0;
  #pragma unroll
  for (int j = 0; j < 4; ++j) {
    int idx = base + j;
    v[j] = (idx < N) ? deg[idx] : 0;
    s += v[j];
  }
  __shared__ int sc[256];
  sc[t] = s;
  __syncthreads();
  for (int off = 1; off < 256; off <<= 1) {
    int x = (t >= off) ? sc[t - off] : 0;
    __syncthreads();
    sc[t] += x;
    __syncthreads();
  }
  int p = bsum[blockIdx.x] + sc[t] - s;
  #pragma unroll
  for (int j = 0; j < 4; ++j) {
    int idx = base + j;
    if (idx < N) {
      offs[idx] = p;
      cursor[idx] = p;
      p += v[j];
    }
  }
}

// ---------------- FUSED: fill (CSR bucket + ssum) overlapped with gemm1
// Role by blockIdx.x % 3: {0,1} -> gemm tile, {2} -> fill chunk.
// gemm: g = (x @ W1) * dinv[row] -> packed bf16x2; LDS = 32KB (bf16 tiles).
__global__ __launch_bounds__(256) void k_fill_gemm(
    const float* __restrict__ x, const float* __restrict__ W,
    const float* __restrict__ dinv, unsigned* __restrict__ gp,
    const int* __restrict__ src, const int* __restrict__ dst,
    int* __restrict__ cursor, int* __restrict__ bucket,
    float* __restrict__ ssum, int M, int E, int nFill, int aligned4) {
  __shared__ unsigned lds[8192];  // 32KB: Ws bf16 [128][64] (4K dw) + xs bf16 [64][128] (4K dw)
  int b = blockIdx.x;
  int role = b - (b / 3) * 3;
  int t = threadIdx.x;

  if (role == 2) {
    // ---- fill role: 1024 edges per chunk, 4 per thread via int4
    int fb = b / 3;
    int nChunks = (E + 1023) / 1024;
    for (int c = fb; c < nChunks; c += nFill) {
      int i = c * 1024 + t * 4;
      if (aligned4 && i + 3 < E) {
        int4 s4 = *(const int4*)(src + i);
        int4 d4 = *(const int4*)(dst + i);
        int p0 = atomicAdd(&cursor[d4.x], 1);
        int p1 = atomicAdd(&cursor[d4.y], 1);
        int p2 = atomicAdd(&cursor[d4.z], 1);
        int p3 = atomicAdd(&cursor[d4.w], 1);
        bucket[p0] = s4.x;
        bucket[p1] = s4.y;
        bucket[p2] = s4.z;
        bucket[p3] = s4.w;
        unsafeAtomicAdd(&ssum[s4.x], dinv[d4.x]);
        unsafeAtomicAdd(&ssum[s4.y], dinv[d4.y]);
        unsafeAtomicAdd(&ssum[s4.z], dinv[d4.z]);
        unsafeAtomicAdd(&ssum[s4.w], dinv[d4.w]);
      } else {
        for (int j = i; j < min(i + 4, E); ++j) {
          int s = src[j], d = dst[j];
          int pos = atomicAdd(&cursor[d], 1);
          bucket[pos] = s;
          unsafeAtomicAdd(&ssum[s], dinv[d]);
        }
      }
    }
    return;
  }

  // ---- gemm role
  int gi = (b / 3) * 2 + role;
  int row0 = (gi >> 1) * 64;
  int coff = (gi & 1) * 64;
  if (row0 >= M) return;
  unsigned* WsU = lds;          // [128][32] dwords (64 bf16 cols)
  unsigned* xsU = lds + 4096;   // [64][64] dwords (128 bf16 cols)

  // stage W[:, coff:coff+64) -> bf16
  for (int i = t; i < 2048; i += 256) {
    int k = i >> 4;          // 16 float4 per row of 64 cols
    int c4 = i & 15;
    float4 w = ((const float4*)(W + (size_t)k * D + coff))[c4];
    *(uint2*)&WsU[k * 32 + c4 * 2] = make_uint2(pack2(w.x, w.y), pack2(w.z, w.w));
  }
  // stage x rows -> bf16
  for (int i = t; i < 2048; i += 256) {
    int r = row0 + (i >> 5);   // 32 float4 per row of 128
    int rc = r < M ? r : M - 1;
    float4 v = ((const float4*)x)[(size_t)rc * (D / 4) + (i & 31)];
    *(uint2*)&xsU[(i >> 5) * 64 + (i & 31) * 2] = make_uint2(pack2(v.x, v.y), pack2(v.z, v.w));
  }
  __syncthreads();

  int cg = t & 15;
  int rg = t >> 4;
  float4 acc[4];
  #pragma unroll
  for (int r = 0; r < 4; ++r) acc[r] = make_float4(0.f, 0.f, 0.f, 0.f);

  for (int k0 = 0; k0 < 128; k0 += 4) {
    uint2 xr[4];
    #pragma unroll
    for (int r = 0; r < 4; ++r)
      xr[r] = *(const uint2*)&xsU[(rg * 4 + r) * 64 + (k0 >> 1)];
    uint2 wv[4];
    #pragma unroll
    for (int j = 0; j < 4; ++j)
      wv[j] = *(const uint2*)&WsU[(k0 + j) * 32 + cg * 2];
    #pragma unroll
    for (int j = 0; j < 4; ++j) {
      float w0 = unpk_lo(wv[j].x), w1 = unpk_hi(wv[j].x);
      float w2 = unpk_lo(wv[j].y), w3 = unpk_hi(wv[j].y);
      #pragma unroll
      for (int r = 0; r < 4; ++r) {
        unsigned xd = (j < 2) ? xr[r].x : xr[r].y;
        float xv = (j & 1) ? unpk_hi(xd) : unpk_lo(xd);
        acc[r].x = fmaf(xv, w0, acc[r].x);
        acc[r].y = fmaf(xv, w1, acc[r].y);
        acc[r].z = fmaf(xv, w2, acc[r].z);
        acc[r].w = fmaf(xv, w3, acc[r].w);
      }
    }
  }

  #pragma unroll
  for (int r = 0; r < 4; ++r) {
    int row = row0 + rg * 4 + r;
    if (row < M) {
      float s = dinv[row];
      float4 a = acc[r];
      *(uint2*)&gp[(size_t)row * 64 + (coff >> 1) + cg * 2] =
          make_uint2(pack2(a.x * s, a.y * s), pack2(a.z * s, a.w * s));
    }
  }
}

// ---------------- fused gather-aggregate + epilogue + weighted reduce (bf16 g)
__global__ __launch_bounds__(256) void k_agg(const unsigned* __restrict__ gp,
                                             const int* __restrict__ bucket,
                                             const int* __restrict__ offs,
                                             const float* __restrict__ dinv,
                                             const float* __restrict__ ssum,
                                             const float* __restrict__ b1,
                                             float* __restrict__ vpart, int N) {
  int lane = threadIdx.x & 63;
  int wid = threadIdx.x >> 6;
  int gwave = blockIdx.x * 4 + wid;
  int nwave = gridDim.x * 4;
  float2 bb = *(const float2*)(b1 + lane * 2);
  float vx = 0.f, vy = 0.f;

  for (int r = gwave; r < N; r += nwave) {
    int beg = offs[r], end = offs[r + 1];
    float ax = 0.f, ay = 0.f;
    int j = beg;
    for (; j + 4 <= end; j += 4) {
      int s0 = bucket[j], s1 = bucket[j + 1], s2 = bucket[j + 2], s3 = bucket[j + 3];
      unsigned v0 = gp[(size_t)s0 * 64 + lane];
      unsigned v1 = gp[(size_t)s1 * 64 + lane];
      unsigned v2 = gp[(size_t)s2 * 64 + lane];
      unsigned v3 = gp[(size_t)s3 * 64 + lane];
      ax += (unpk_lo(v0) + unpk_lo(v1)) + (unpk_lo(v2) + unpk_lo(v3));
      ay += (unpk_hi(v0) + unpk_hi(v1)) + (unpk_hi(v2) + unpk_hi(v3));
    }
    for (; j < end; ++j) {
      unsigned v = gp[(size_t)bucket[j] * 64 + lane];
      ax += unpk_lo(v);
      ay += unpk_hi(v);
    }
    unsigned gr = gp[(size_t)r * 64 + lane];
    float di = dinv[r];
    float w = di * (ssum[r] + di);
    float hx = fmaxf(fmaf(di, ax + unpk_lo(gr), bb.x), 0.f);
    float hy = fmaxf(fmaf(di, ay + unpk_hi(gr), bb.y), 0.f);
    vx = fmaf(w, hx, vx);
    vy = fmaf(w, hy, vy);
  }

  __shared__ float2 red[256];
  red[threadIdx.x] = make_float2(vx, vy);
  __syncthreads();
  if (threadIdx.x < 64) {
    float2 a = red[threadIdx.x], b = red[threadIdx.x + 64];
    float2 c = red[threadIdx.x + 128], d = red[threadIdx.x + 192];
    float2 o = make_float2((a.x + b.x) + (c.x + d.x), (a.y + b.y) + (c.y + d.y));
    *(float2*)(vpart + (size_t)blockIdx.x * D + lane * 2) = o;
  }
}

// ---------------- final: v = sum partials; out = (1/N)*v@W2 + b2
__global__ __launch_bounds__(1024) void k_final(const float* __restrict__ vpart,
                                                int npart,
                                                const float* __restrict__ W2,
                                                const float* __restrict__ b2,
                                                float* __restrict__ out, float invN) {
  __shared__ float seg[8][128];
  __shared__ float vs[128];
  int t = threadIdx.x;
  int c = t & 127, sg = t >> 7;
  float s = 0.f;
  for (int b = sg; b < npart; b += 8) s += vpart[(size_t)b * D + c];
  seg[sg][c] = s;
  __syncthreads();
  if (t < 128) {
    float tot = 0.f;
    #pragma unroll
    for (int k = 0; k < 8; ++k) tot += seg[k][c];
    vs[c] = tot;
  }
  __syncthreads();
  if (t < 128) {
    float o = 0.f;
    for (int k = 0; k < 128; ++k) o = fmaf(vs[k], W2[k * D + c], o);
    out[c] = fmaf(o, invN, b2[c]);
  }
}

extern "C" void kernel_launch(void* const* d_in, const int* in_sizes, int n_in,
                              void* d_out, int out_size, void* d_ws, size_t ws_size,
                              hipStream_t stream) {
  const float* x  = (const float*)d_in[0];
  const int*   ei = (const int*)d_in[1];
  const float* W1 = (const float*)d_in[2];
  const float* b1 = (const float*)d_in[3];
  const float* W2 = (const float*)d_in[4];
  const float* b2 = (const float*)d_in[5];
  float* out = (float*)d_out;

  int N = in_sizes[0] / D;
  int E = in_sizes[1] / 2;
  const int* src = ei;
  const int* dst = ei + E;

  const int NB_SCAN = (N + 1023) / 1024;
  const int AGG_BLOCKS = 2048;

  char* p = (char*)d_ws;
  int*   deg    = (int*)p;        p += (size_t)N * 4;
  float* ssum   = (float*)p;      p += (size_t)N * 4;
  float* dinv   = (float*)p;      p += (size_t)N * 4;
  int*   offs   = (int*)p;        p += (size_t)(N + 1) * 4;
  int*   cursor = (int*)p;        p += (size_t)N * 4;
  int*   bsum   = (int*)p;        p += 128 * 4;
  int*   bucket = (int*)p;        p += (size_t)E * 4;
  p = (char*)(((uintptr_t)p + 255) & ~(uintptr_t)255);
  unsigned* gp  = (unsigned*)p;   p += (size_t)N * 64 * 4;
  float* vpart  = (float*)p;

  hipMemsetAsync(d_ws, 0, (size_t)(2 * N) * sizeof(float), stream);

  k_deg<<<(E + 1023) / 1024, 256, 0, stream>>>(dst, deg, E);
  k_dinv<<<(N + 255) / 256, 256, 0, stream>>>(deg, dinv, N);

  k_scan1<<<NB_SCAN, 256, 0, stream>>>(deg, bsum, N);
  k_scan2<<<1, 128, 0, stream>>>(bsum, NB_SCAN, offs, N);
  k_scan3<<<NB_SCAN, 256, 0, stream>>>(deg, bsum, offs, cursor, N);

  // fused fill + gemm1: 3K blocks, K = row tiles (2 gemm roles + 1 fill role)
  int RT = (N + 63) / 64;            // row tiles (gemm needs 2*RT blocks)
  int nFill = RT;                    // fill blocks (grid-stride over chunks)
  int aligned4 = ((E & 3) == 0) ? 1 : 0;
  k_fill_gemm<<<3 * RT, 256, 0, stream>>>(x, W1, dinv, gp, src, dst,
                                          cursor, bucket, ssum, N, E, nFill, aligned4);

  k_agg<<<AGG_BLOCKS, 256, 0, stream>>>(gp, bucket, offs, dinv, ssum, b1, vpart, N);

  k_final<<<1, 1024, 0, stream>>>(vpart, AGG_BLOCKS, W2, b2, out, 1.0f / N);
}

// Round 5
// 424.825 us; speedup vs baseline: 4.5102x; 1.1010x over previous
//
#include <hip/hip_runtime.h>

#define D 128

// ---- bf16 pack helpers (round-to-nearest-even)
__device__ inline unsigned bfr(float f) {
  unsigned u = __float_as_uint(f);
  return (u + 0x7fffu + ((u >> 16) & 1u)) >> 16;
}
__device__ inline unsigned pack2(float lo, float hi) {
  return bfr(lo) | (bfr(hi) << 16);
}
__device__ inline float unpk_lo(unsigned v) { return __uint_as_float(v << 16); }
__device__ inline float unpk_hi(unsigned v) { return __uint_as_float(v & 0xffff0000u); }

// ---------------- degree histogram + per-edge rank: rank[e] = old deg[dst[e]]++
__global__ __launch_bounds__(256) void k_deg_rank(const int* __restrict__ dst,
                                                  int* __restrict__ deg,
                                                  int* __restrict__ rank, int E) {
  int i = (blockIdx.x * 256 + threadIdx.x) * 4;
  if (i + 3 < E) {
    int4 d4 = *(const int4*)(dst + i);
    int4 r4;
    r4.x = atomicAdd(&deg[d4.x], 1);
    r4.y = atomicAdd(&deg[d4.y], 1);
    r4.z = atomicAdd(&deg[d4.z], 1);
    r4.w = atomicAdd(&deg[d4.w], 1);
    *(int4*)(rank + i) = r4;
  } else {
    for (int j = i; j < E; ++j) rank[j] = atomicAdd(&deg[dst[j]], 1);
  }
}

// ---------------- scan stage 1: per-block (1024 elems) sums
__global__ __launch_bounds__(256) void k_scan1(const int* __restrict__ deg,
                                               int* __restrict__ bsum, int N) {
  int t = threadIdx.x;
  int base = blockIdx.x * 1024;
  int s = 0;
  for (int i = t; i < 1024; i += 256) {
    int idx = base + i;
    if (idx < N) s += deg[idx];
  }
  __shared__ int red[256];
  red[t] = s;
  __syncthreads();
  for (int off = 128; off > 0; off >>= 1) {
    if (t < off) red[t] += red[t + off];
    __syncthreads();
  }
  if (t == 0) bsum[blockIdx.x] = red[0];
}

// ---------------- scan stage 2: parallel exclusive scan of block sums (nb <= 128)
__global__ __launch_bounds__(128) void k_scan2(int* __restrict__ bsum, int nb,
                                               int* __restrict__ offs, int N) {
  __shared__ int sc[128];
  int t = threadIdx.x;
  int v = (t < nb) ? bsum[t] : 0;
  sc[t] = v;
  __syncthreads();
  #pragma unroll
  for (int off = 1; off < 128; off <<= 1) {
    int x = (t >= off) ? sc[t - off] : 0;
    __syncthreads();
    sc[t] += x;
    __syncthreads();
  }
  if (t < nb) bsum[t] = sc[t] - v;        // exclusive
  if (t == nb - 1) offs[N] = sc[t];       // total == E
}

// ---------------- scan stage 3: in-block exclusive scan -> offs; fused dinv
__global__ __launch_bounds__(256) void k_scan3(const int* __restrict__ deg,
                                               const int* __restrict__ bsum,
                                               int* __restrict__ offs,
                                               float* __restrict__ dinv, int N) {
  int t = threadIdx.x;
  int base = blockIdx.x * 1024 + t * 4;
  int v[4];
  int s = 0;
  #pragma unroll
  for (int j = 0; j < 4; ++j) {
    int idx = base + j;
    v[j] = (idx < N) ? deg[idx] : 0;
    s += v[j];
  }
  __shared__ int sc[256];
  sc[t] = s;
  __syncthreads();
  for (int off = 1; off < 256; off <<= 1) {
    int x = (t >= off) ? sc[t - off] : 0;
    __syncthreads();
    sc[t] += x;
    __syncthreads();
  }
  int p = bsum[blockIdx.x] + sc[t] - s;
  #pragma unroll
  for (int j = 0; j < 4; ++j) {
    int idx = base + j;
    if (idx < N) {
      offs[idx] = p;
      dinv[idx] = rsqrtf((float)v[j] + 1.0f);
      p += v[j];
    }
  }
}

// ---------------- FUSED: fill (atomic-free bucket write + ssum) overlapped with gemm1
// Role by blockIdx.x % 3: {0,1} -> gemm tile, {2} -> fill chunk.
__global__ __launch_bounds__(256) void k_fill_gemm(
    const float* __restrict__ x, const float* __restrict__ W,
    const float* __restrict__ dinv, unsigned* __restrict__ gp,
    const int* __restrict__ src, const int* __restrict__ dst,
    const int* __restrict__ rank, const int* __restrict__ offs,
    int* __restrict__ bucket, float* __restrict__ ssum,
    int M, int E, int nFill, int aligned4) {
  __shared__ unsigned lds[8192];  // 32KB bf16 tiles
  int b = blockIdx.x;
  int role = b - (b / 3) * 3;
  int t = threadIdx.x;

  if (role == 2) {
    // ---- fill role: 1024 edges per chunk, 4 per thread via int4, no RMW chain
    int fb = b / 3;
    int nChunks = (E + 1023) / 1024;
    for (int c = fb; c < nChunks; c += nFill) {
      int i = c * 1024 + t * 4;
      if (aligned4 && i + 3 < E) {
        int4 s4 = *(const int4*)(src + i);
        int4 d4 = *(const int4*)(dst + i);
        int4 r4 = *(const int4*)(rank + i);
        int p0 = offs[d4.x] + r4.x;
        int p1 = offs[d4.y] + r4.y;
        int p2 = offs[d4.z] + r4.z;
        int p3 = offs[d4.w] + r4.w;
        bucket[p0] = s4.x;
        bucket[p1] = s4.y;
        bucket[p2] = s4.z;
        bucket[p3] = s4.w;
        unsafeAtomicAdd(&ssum[s4.x], dinv[d4.x]);
        unsafeAtomicAdd(&ssum[s4.y], dinv[d4.y]);
        unsafeAtomicAdd(&ssum[s4.z], dinv[d4.z]);
        unsafeAtomicAdd(&ssum[s4.w], dinv[d4.w]);
      } else {
        for (int j = i; j < min(i + 4, E); ++j) {
          int s = src[j], d = dst[j];
          bucket[offs[d] + rank[j]] = s;
          unsafeAtomicAdd(&ssum[s], dinv[d]);
        }
      }
    }
    return;
  }

  // ---- gemm role: g = (x @ W1) * dinv[row] -> packed bf16x2
  int gi = (b / 3) * 2 + role;
  int row0 = (gi >> 1) * 64;
  int coff = (gi & 1) * 64;
  if (row0 >= M) return;
  unsigned* WsU = lds;          // [128][32] dwords (64 bf16 cols)
  unsigned* xsU = lds + 4096;   // [64][64] dwords (128 bf16 cols)

  for (int i = t; i < 2048; i += 256) {
    int k = i >> 4;
    int c4 = i & 15;
    float4 w = ((const float4*)(W + (size_t)k * D + coff))[c4];
    *(uint2*)&WsU[k * 32 + c4 * 2] = make_uint2(pack2(w.x, w.y), pack2(w.z, w.w));
  }
  for (int i = t; i < 2048; i += 256) {
    int r = row0 + (i >> 5);
    int rc = r < M ? r : M - 1;
    float4 v = ((const float4*)x)[(size_t)rc * (D / 4) + (i & 31)];
    *(uint2*)&xsU[(i >> 5) * 64 + (i & 31) * 2] = make_uint2(pack2(v.x, v.y), pack2(v.z, v.w));
  }
  __syncthreads();

  int cg = t & 15;
  int rg = t >> 4;
  float4 acc[4];
  #pragma unroll
  for (int r = 0; r < 4; ++r) acc[r] = make_float4(0.f, 0.f, 0.f, 0.f);

  for (int k0 = 0; k0 < 128; k0 += 4) {
    uint2 xr[4];
    #pragma unroll
    for (int r = 0; r < 4; ++r)
      xr[r] = *(const uint2*)&xsU[(rg * 4 + r) * 64 + (k0 >> 1)];
    uint2 wv[4];
    #pragma unroll
    for (int j = 0; j < 4; ++j)
      wv[j] = *(const uint2*)&WsU[(k0 + j) * 32 + cg * 2];
    #pragma unroll
    for (int j = 0; j < 4; ++j) {
      float w0 = unpk_lo(wv[j].x), w1 = unpk_hi(wv[j].x);
      float w2 = unpk_lo(wv[j].y), w3 = unpk_hi(wv[j].y);
      #pragma unroll
      for (int r = 0; r < 4; ++r) {
        unsigned xd = (j < 2) ? xr[r].x : xr[r].y;
        float xv = (j & 1) ? unpk_hi(xd) : unpk_lo(xd);
        acc[r].x = fmaf(xv, w0, acc[r].x);
        acc[r].y = fmaf(xv, w1, acc[r].y);
        acc[r].z = fmaf(xv, w2, acc[r].z);
        acc[r].w = fmaf(xv, w3, acc[r].w);
      }
    }
  }

  #pragma unroll
  for (int r = 0; r < 4; ++r) {
    int row = row0 + rg * 4 + r;
    if (row < M) {
      float s = dinv[row];
      float4 a = acc[r];
      *(uint2*)&gp[(size_t)row * 64 + (coff >> 1) + cg * 2] =
          make_uint2(pack2(a.x * s, a.y * s), pack2(a.z * s, a.w * s));
    }
  }
}

// ---------------- fused gather-aggregate + epilogue + weighted reduce (bf16 g)
__global__ __launch_bounds__(256) void k_agg(const unsigned* __restrict__ gp,
                                             const int* __restrict__ bucket,
                                             const int* __restrict__ offs,
                                             const float* __restrict__ dinv,
                                             const float* __restrict__ ssum,
                                             const float* __restrict__ b1,
                                             float* __restrict__ vpart, int N) {
  int lane = threadIdx.x & 63;
  int wid = threadIdx.x >> 6;
  int gwave = blockIdx.x * 4 + wid;
  int nwave = gridDim.x * 4;
  float2 bb = *(const float2*)(b1 + lane * 2);
  float vx = 0.f, vy = 0.f;

  for (int r = gwave; r < N; r += nwave) {
    int beg = offs[r], end = offs[r + 1];
    float ax = 0.f, ay = 0.f;
    int j = beg;
    for (; j + 4 <= end; j += 4) {
      int s0 = bucket[j], s1 = bucket[j + 1], s2 = bucket[j + 2], s3 = bucket[j + 3];
      unsigned v0 = gp[(size_t)s0 * 64 + lane];
      unsigned v1 = gp[(size_t)s1 * 64 + lane];
      unsigned v2 = gp[(size_t)s2 * 64 + lane];
      unsigned v3 = gp[(size_t)s3 * 64 + lane];
      ax += (unpk_lo(v0) + unpk_lo(v1)) + (unpk_lo(v2) + unpk_lo(v3));
      ay += (unpk_hi(v0) + unpk_hi(v1)) + (unpk_hi(v2) + unpk_hi(v3));
    }
    for (; j < end; ++j) {
      unsigned v = gp[(size_t)bucket[j] * 64 + lane];
      ax += unpk_lo(v);
      ay += unpk_hi(v);
    }
    unsigned gr = gp[(size_t)r * 64 + lane];
    float di = dinv[r];
    float w = di * (ssum[r] + di);
    float hx = fmaxf(fmaf(di, ax + unpk_lo(gr), bb.x), 0.f);
    float hy = fmaxf(fmaf(di, ay + unpk_hi(gr), bb.y), 0.f);
    vx = fmaf(w, hx, vx);
    vy = fmaf(w, hy, vy);
  }

  __shared__ float2 red[256];
  red[threadIdx.x] = make_float2(vx, vy);
  __syncthreads();
  if (threadIdx.x < 64) {
    float2 a = red[threadIdx.x], b = red[threadIdx.x + 64];
    float2 c = red[threadIdx.x + 128], d = red[threadIdx.x + 192];
    float2 o = make_float2((a.x + b.x) + (c.x + d.x), (a.y + b.y) + (c.y + d.y));
    *(float2*)(vpart + (size_t)blockIdx.x * D + lane * 2) = o;
  }
}

// ---------------- final: v = sum partials; out = (1/N)*v@W2 + b2
__global__ __launch_bounds__(1024) void k_final(const float* __restrict__ vpart,
                                                int npart,
                                                const float* __restrict__ W2,
                                                const float* __restrict__ b2,
                                                float* __restrict__ out, float invN) {
  __shared__ float seg[8][128];
  __shared__ float vs[128];
  int t = threadIdx.x;
  int c = t & 127, sg = t >> 7;
  float s = 0.f;
  for (int b = sg; b < npart; b += 8) s += vpart[(size_t)b * D + c];
  seg[sg][c] = s;
  __syncthreads();
  if (t < 128) {
    float tot = 0.f;
    #pragma unroll
    for (int k = 0; k < 8; ++k) tot += seg[k][c];
    vs[c] = tot;
  }
  __syncthreads();
  if (t < 128) {
    float o = 0.f;
    for (int k = 0; k < 128; ++k) o = fmaf(vs[k], W2[k * D + c], o);
    out[c] = fmaf(o, invN, b2[c]);
  }
}

extern "C" void kernel_launch(void* const* d_in, const int* in_sizes, int n_in,
                              void* d_out, int out_size, void* d_ws, size_t ws_size,
                              hipStream_t stream) {
  const float* x  = (const float*)d_in[0];
  const int*   ei = (const int*)d_in[1];
  const float* W1 = (const float*)d_in[2];
  const float* b1 = (const float*)d_in[3];
  const float* W2 = (const float*)d_in[4];
  const float* b2 = (const float*)d_in[5];
  float* out = (float*)d_out;

  int N = in_sizes[0] / D;
  int E = in_sizes[1] / 2;
  const int* src = ei;
  const int* dst = ei + E;

  const int NB_SCAN = (N + 1023) / 1024;
  const int AGG_BLOCKS = 2048;

  char* p = (char*)d_ws;
  int*   deg    = (int*)p;        p += (size_t)N * 4;
  float* ssum   = (float*)p;      p += (size_t)N * 4;
  float* dinv   = (float*)p;      p += (size_t)N * 4;
  int*   offs   = (int*)p;        p += (size_t)(N + 1) * 4;
  int*   bsum   = (int*)p;        p += 128 * 4;
  int*   rank   = (int*)p;        p += (size_t)E * 4;
  int*   bucket = (int*)p;        p += (size_t)E * 4;
  p = (char*)(((uintptr_t)p + 255) & ~(uintptr_t)255);
  unsigned* gp  = (unsigned*)p;   p += (size_t)N * 64 * 4;
  float* vpart  = (float*)p;

  // zero: deg + ssum (contiguous)
  hipMemsetAsync(d_ws, 0, (size_t)(2 * N) * sizeof(float), stream);

  k_deg_rank<<<(E + 1023) / 1024, 256, 0, stream>>>(dst, deg, rank, E);

  k_scan1<<<NB_SCAN, 256, 0, stream>>>(deg, bsum, N);
  k_scan2<<<1, 128, 0, stream>>>(bsum, NB_SCAN, offs, N);
  k_scan3<<<NB_SCAN, 256, 0, stream>>>(deg, bsum, offs, dinv, N);

  int RT = (N + 63) / 64;
  int nFill = RT;
  int aligned4 = ((E & 3) == 0) ? 1 : 0;
  k_fill_gemm<<<3 * RT, 256, 0, stream>>>(x, W1, dinv, gp, src, dst, rank, offs,
                                          bucket, ssum, N, E, nFill, aligned4);

  k_agg<<<AGG_BLOCKS, 256, 0, stream>>>(gp, bucket, offs, dinv, ssum, b1, vpart, N);

  k_final<<<1, 1024, 0, stream>>>(vpart, AGG_BLOCKS, W2, b2, out, 1.0f / N);
}